// Round 3
// baseline (249.988 us; speedup 1.0000x reference)
//
#include <hip/hip_runtime.h>

// Fused MLPKAN, "lane = batch" layout.
// Block = 64 batches x 4 waves; wave w owns i in [16w, 16w+16) for both layers.
// - Weights: addresses depend only on loop counters -> wave-uniform -> s_load
//   (scalar pipe + K$/L2), zero vector-memory traffic in the hot loop.
// - x, h: LDS, rows padded to 65 floats -> column reads are 2-way (free).
// - Cross-wave i-reduction: ds_add_f32 (LDS atomicAdd) into hs / os.
// - H=2 hidden pairs as float2 ext-vectors -> v_pk_fma_f32 candidates.
// Grid = 256 blocks (1/CU); latency hiding via 64 independent acc chains.

typedef float v2f __attribute__((ext_vector_type(2)));

#define BATCH 16384

__global__ __launch_bounds__(256) void kan_fused(
    const float* __restrict__ x,
    const float* __restrict__ A1, const float* __restrict__ a1,
    const float* __restrict__ A2, const float* __restrict__ a2,
    const float* __restrict__ A3, const float* __restrict__ a3,
    const float* __restrict__ B1, const float* __restrict__ c1,
    const float* __restrict__ B2, const float* __restrict__ c2,
    const float* __restrict__ B3, const float* __restrict__ c3,
    float* __restrict__ out)
{
    __shared__ float xs[64][65];
    __shared__ float hs[64][65];
    __shared__ float os[64][17];

    const int t    = threadIdx.x;
    const int lane = t & 63;
    const int wave = t >> 6;
    const int bB0  = blockIdx.x * 64;

    // zero accumure LDS (re-poisoned to 0xAA before every launch)
    for (int k = t; k < 64 * 65; k += 256) (&hs[0][0])[k] = 0.f;
    for (int k = t; k < 64 * 17; k += 256) (&os[0][0])[k] = 0.f;

    // stage x tile [64 batches][64 feats], coalesced float4
    for (int k = t * 4; k < 64 * 64; k += 256 * 4) {
        const float4 v = *(const float4*)(x + (long)bB0 * 64 + k);
        const int bb = k >> 6, c = k & 63;
        xs[bb][c] = v.x; xs[bb][c + 1] = v.y; xs[bb][c + 2] = v.z; xs[bb][c + 3] = v.w;
    }
    __syncthreads();

    const int b  = lane;
    const int i0 = wave * 16;
    const v2f zz = {0.f, 0.f};

    // ---------------- layer 0: 64 -> 64 ----------------
    float acc[64];
#pragma unroll
    for (int o = 0; o < 64; ++o) acc[o] = 0.f;

    float xv = xs[b][i0];
#pragma unroll 1
    for (int ii = 0; ii < 16; ++ii) {
        const int i = i0 + ii;
        const float xvn = xs[b][i0 + ((ii + 1) & 15)];   // next-iter prefetch
        const v2f xd = {xv, xv};
        const int nb = i << 6;
#pragma unroll
        for (int o = 0; o < 64; ++o) {
            const int n = nb + o;                         // uniform -> s_load
            const v2f   w1 = *(const v2f*)(A1 + 2 * n);
            const v2f   d1 = *(const v2f*)(a1 + 2 * n);
            const float4 w2 = *(const float4*)(A2 + 4 * n);
            const v2f   d2 = *(const v2f*)(a2 + 2 * n);
            const v2f   w3 = *(const v2f*)(A3 + 2 * n);
            v2f m = __builtin_elementwise_fma(xd, w1, d1);
            m = __builtin_elementwise_max(m, zz);
            const v2f mm0 = {m.x, m.x};
            const v2f mm1 = {m.y, m.y};
            const v2f c0  = {w2.x, w2.z};
            const v2f c1v = {w2.y, w2.w};
            v2f tt = __builtin_elementwise_fma(c1v, mm1, d2);
            tt = __builtin_elementwise_fma(c0, mm0, tt);
            tt = __builtin_elementwise_max(tt, zz);
            acc[o] += fmaf(w3.x, tt.x, fmaf(w3.y, tt.y, a3[n]));
        }
        xv = xvn;
    }
#pragma unroll
    for (int o = 0; o < 64; ++o)
        atomicAdd(&hs[b][o], acc[o]);                     // ds_add_f32, 2-way banks
    __syncthreads();

    // ---------------- layer 1: 64 -> 16 ----------------
    float acc1[16];
#pragma unroll
    for (int o = 0; o < 16; ++o) acc1[o] = 0.f;

    float hv = hs[b][i0];
#pragma unroll 1
    for (int ii = 0; ii < 16; ++ii) {
        const int i = i0 + ii;
        const float hvn = hs[b][i0 + ((ii + 1) & 15)];
        const v2f xd = {hv, hv};
        const int nb = i << 4;
#pragma unroll
        for (int o = 0; o < 16; ++o) {
            const int n = nb + o;
            const v2f   w1 = *(const v2f*)(B1 + 2 * n);
            const v2f   d1 = *(const v2f*)(c1 + 2 * n);
            const float4 w2 = *(const float4*)(B2 + 4 * n);
            const v2f   d2 = *(const v2f*)(c2 + 2 * n);
            const v2f   w3 = *(const v2f*)(B3 + 2 * n);
            v2f m = __builtin_elementwise_fma(xd, w1, d1);
            m = __builtin_elementwise_max(m, zz);
            const v2f mm0 = {m.x, m.x};
            const v2f mm1 = {m.y, m.y};
            const v2f c0  = {w2.x, w2.z};
            const v2f c1v = {w2.y, w2.w};
            v2f tt = __builtin_elementwise_fma(c1v, mm1, d2);
            tt = __builtin_elementwise_fma(c0, mm0, tt);
            tt = __builtin_elementwise_max(tt, zz);
            acc1[o] += fmaf(w3.x, tt.x, fmaf(w3.y, tt.y, c3[n]));
        }
        hv = hvn;
    }
#pragma unroll
    for (int o = 0; o < 16; ++o)
        atomicAdd(&os[b][o], acc1[o]);
    __syncthreads();

    // ---------------- store: 1024 floats, coalesced float4 ----------------
    {
        const int f  = t * 4;
        const int bb = f >> 4, o = f & 15;
        float4 v;
        v.x = os[bb][o];     v.y = os[bb][o + 1];
        v.z = os[bb][o + 2]; v.w = os[bb][o + 3];
        *(float4*)(out + (long)bB0 * 16 + f) = v;
    }
}

extern "C" void kernel_launch(void* const* d_in, const int* in_sizes, int n_in,
                              void* d_out, int out_size, void* d_ws, size_t ws_size,
                              hipStream_t stream) {
    const float* x     = (const float*)d_in[0];
    const float* l0_W1 = (const float*)d_in[1];
    const float* l0_b1 = (const float*)d_in[2];
    const float* l0_W2 = (const float*)d_in[3];
    const float* l0_b2 = (const float*)d_in[4];
    const float* l0_W3 = (const float*)d_in[5];
    const float* l0_b3 = (const float*)d_in[6];
    const float* l1_W1 = (const float*)d_in[7];
    const float* l1_b1 = (const float*)d_in[8];
    const float* l1_W2 = (const float*)d_in[9];
    const float* l1_b2 = (const float*)d_in[10];
    const float* l1_W3 = (const float*)d_in[11];
    const float* l1_b3 = (const float*)d_in[12];

    float* outp = (float*)d_out;

    dim3 blk(256);
    dim3 grid(BATCH / 64);   // 256 blocks, 1 per CU
    hipLaunchKernelGGL(kan_fused, grid, blk, 0, stream,
                       x,
                       l0_W1, l0_b1, l0_W2, l0_b2, l0_W3, l0_b3,
                       l1_W1, l1_b1, l1_W2, l1_b2, l1_W3, l1_b3,
                       outp);
}

// Round 4
// 145.122 us; speedup vs baseline: 1.7226x; 1.7226x over previous
//
#include <hip/hip_runtime.h>

// Fused MLPKAN, lane=o layout with 16 batches per weight fetch.
// Block = 32 batches, 4 waves; wave = (ih, bh): ih = i-half, bh = batch-half.
//   Layer0: lane = o (64 lane-distinct subnets per i): coalesced float2/float4
//           weight loads; 32 i x 16 b per wave -> 52B weights amortized over 16 b.
//   Layer1: lane = iq*16+o1 (64 lane-distinct subnets); 8 i x 16 b per wave;
//           iq partials reduced with shfl_xor(16,32); ih partials via LDS.
//   Activations transposed in LDS ([i][b], pad 36) -> ds_read_b128 broadcasts.
// Grid = 512 -> 2 blocks/CU -> 8 waves/CU -> 2 waves/SIMD.

typedef float v2f __attribute__((ext_vector_type(2)));

#define BATCH 16384
#define TB    32

__global__ __launch_bounds__(256, 2) void kan_fused(
    const float* __restrict__ x,
    const float* __restrict__ A1, const float* __restrict__ a1,
    const float* __restrict__ A2, const float* __restrict__ a2,
    const float* __restrict__ A3, const float* __restrict__ a3,
    const float* __restrict__ B1, const float* __restrict__ c1,
    const float* __restrict__ B2, const float* __restrict__ c2,
    const float* __restrict__ B3, const float* __restrict__ c3,
    float* __restrict__ out)
{
    __shared__ float xs[64][36];        // x transposed: xs[i][b], pad 36
    __shared__ float hp[2][TB][64];     // layer0 partials per i-half, b-major
    __shared__ float ht[64][36];        // h transposed: ht[i][b], pad 36
    __shared__ float op[2][TB][16];     // layer1 partials per i-half

    const int t    = threadIdx.x;
    const int lane = t & 63;
    const int wave = t >> 6;
    const int ih   = wave & 1;          // i-half: [32*ih, 32*ih+32)
    const int bh   = wave >> 1;         // batch-half: [16*bh, 16*bh+16)
    const int bB0  = blockIdx.x * TB;

    // ---- stage x transposed: x[b][i] -> xs[i][b] ----
    for (int k = t * 4; k < TB * 64; k += 256 * 4) {
        const float4 v = *(const float4*)(x + (long)bB0 * 64 + k);
        const int b = k >> 6, i = k & 63;
        xs[i][b] = v.x; xs[i + 1][b] = v.y; xs[i + 2][b] = v.z; xs[i + 3][b] = v.w;
    }
    __syncthreads();

    const v2f zz = {0.f, 0.f};

    // ================= layer 0: 64 -> 64 =================
    {
        const int o  = lane;
        const int n0 = (32 * ih) * 64 + o;
        const float* pA1 = A1 + 2 * n0;
        const float* pa1 = a1 + 2 * n0;
        const float* pA2 = A2 + 4 * n0;
        const float* pa2 = a2 + 2 * n0;
        const float* pA3 = A3 + 2 * n0;
        const float* pa3 = a3 + n0;

        float acc[16];
#pragma unroll
        for (int j = 0; j < 16; ++j) acc[j] = 0.f;
        float bsum = 0.f;

#pragma unroll 4
        for (int ii = 0; ii < 32; ++ii) {
            const int i = 32 * ih + ii;
            const v2f    w1 = *(const v2f*)pA1;    pA1 += 128;
            const v2f    d1 = *(const v2f*)pa1;    pa1 += 128;
            const float4 w2 = *(const float4*)pA2; pA2 += 256;
            const v2f    d2 = *(const v2f*)pa2;    pa2 += 128;
            const v2f    w3 = *(const v2f*)pA3;    pA3 += 128;
            bsum += *pa3;                          pa3 += 64;
            const v2f c0  = {w2.x, w2.z};
            const v2f c1v = {w2.y, w2.w};
            const float4 xv0 = *(const float4*)&xs[i][16 * bh];      // broadcast
            const float4 xv1 = *(const float4*)&xs[i][16 * bh + 4];
            const float4 xv2 = *(const float4*)&xs[i][16 * bh + 8];
            const float4 xv3 = *(const float4*)&xs[i][16 * bh + 12];
            const float xv[16] = {xv0.x, xv0.y, xv0.z, xv0.w,
                                  xv1.x, xv1.y, xv1.z, xv1.w,
                                  xv2.x, xv2.y, xv2.z, xv2.w,
                                  xv3.x, xv3.y, xv3.z, xv3.w};
#pragma unroll
            for (int j = 0; j < 16; ++j) {
                const v2f xd = {xv[j], xv[j]};
                v2f m = __builtin_elementwise_fma(xd, w1, d1);
                m = __builtin_elementwise_max(m, zz);
                const v2f mm0 = {m.x, m.x};
                const v2f mm1 = {m.y, m.y};
                v2f tt = __builtin_elementwise_fma(c1v, mm1, d2);
                tt = __builtin_elementwise_fma(c0, mm0, tt);
                tt = __builtin_elementwise_max(tt, zz);
                acc[j] = fmaf(w3.x, tt.x, fmaf(w3.y, tt.y, acc[j]));
            }
        }
#pragma unroll
        for (int j = 0; j < 16; ++j)
            hp[ih][16 * bh + j][o] = acc[j] + bsum;   // stride-64 rows: 2-way, free
    }
    __syncthreads();

    // ---- combine i-halves + transpose: ht[i][b] = hp[0][b][i] + hp[1][b][i] ----
    for (int k = t; k < TB * 64; k += 256) {
        const int b = k >> 6, i = k & 63;
        ht[i][b] = hp[0][b][i] + hp[1][b][i];
    }
    __syncthreads();

    // ================= layer 1: 64 -> 16 =================
    {
        const int o1 = lane & 15;
        const int iq = lane >> 4;
        const int i0 = 32 * ih + 8 * iq;
        const int n0 = i0 * 16 + o1;
        const float* pB1 = B1 + 2 * n0;
        const float* pc1 = c1 + 2 * n0;
        const float* pB2 = B2 + 4 * n0;
        const float* pc2 = c2 + 2 * n0;
        const float* pB3 = B3 + 2 * n0;
        const float* pc3 = c3 + n0;

        float acc[16];
#pragma unroll
        for (int j = 0; j < 16; ++j) acc[j] = 0.f;
        float bsum = 0.f;

#pragma unroll
        for (int ii = 0; ii < 8; ++ii) {
            const int i = i0 + ii;
            const v2f    w1 = *(const v2f*)pB1;    pB1 += 32;
            const v2f    d1 = *(const v2f*)pc1;    pc1 += 32;
            const float4 w2 = *(const float4*)pB2; pB2 += 64;
            const v2f    d2 = *(const v2f*)pc2;    pc2 += 32;
            const v2f    w3 = *(const v2f*)pB3;    pB3 += 32;
            bsum += *pc3;                          pc3 += 16;
            const v2f c0  = {w2.x, w2.z};
            const v2f c1v = {w2.y, w2.w};
            const float4 hv0 = *(const float4*)&ht[i][16 * bh];
            const float4 hv1 = *(const float4*)&ht[i][16 * bh + 4];
            const float4 hv2 = *(const float4*)&ht[i][16 * bh + 8];
            const float4 hv3 = *(const float4*)&ht[i][16 * bh + 12];
            const float hv[16] = {hv0.x, hv0.y, hv0.z, hv0.w,
                                  hv1.x, hv1.y, hv1.z, hv1.w,
                                  hv2.x, hv2.y, hv2.z, hv2.w,
                                  hv3.x, hv3.y, hv3.z, hv3.w};
#pragma unroll
            for (int j = 0; j < 16; ++j) {
                const v2f xd = {hv[j], hv[j]};
                v2f m = __builtin_elementwise_fma(xd, w1, d1);
                m = __builtin_elementwise_max(m, zz);
                const v2f mm0 = {m.x, m.x};
                const v2f mm1 = {m.y, m.y};
                v2f tt = __builtin_elementwise_fma(c1v, mm1, d2);
                tt = __builtin_elementwise_fma(c0, mm0, tt);
                tt = __builtin_elementwise_max(tt, zz);
                acc[j] = fmaf(w3.x, tt.x, fmaf(w3.y, tt.y, acc[j]));
            }
        }
        // reduce over iq (lanes 16 apart), then write per-(ih) partial
#pragma unroll
        for (int j = 0; j < 16; ++j) {
            float v = acc[j] + bsum;
            v += __shfl_xor(v, 16, 64);
            v += __shfl_xor(v, 32, 64);
            if (iq == 0) op[ih][16 * bh + j][o1] = v;
        }
    }
    __syncthreads();

    // ---- store: out = op[0] + op[1], 512 floats, float4 coalesced ----
    if (t < 128) {
        const int f = t * 4;
        const float4 u = *(const float4*)(&op[0][0][0] + f);
        const float4 v = *(const float4*)(&op[1][0][0] + f);
        float4 r;
        r.x = u.x + v.x; r.y = u.y + v.y; r.z = u.z + v.z; r.w = u.w + v.w;
        *(float4*)(out + (long)bB0 * 16 + f) = r;
    }
}

extern "C" void kernel_launch(void* const* d_in, const int* in_sizes, int n_in,
                              void* d_out, int out_size, void* d_ws, size_t ws_size,
                              hipStream_t stream) {
    const float* x     = (const float*)d_in[0];
    const float* l0_W1 = (const float*)d_in[1];
    const float* l0_b1 = (const float*)d_in[2];
    const float* l0_W2 = (const float*)d_in[3];
    const float* l0_b2 = (const float*)d_in[4];
    const float* l0_W3 = (const float*)d_in[5];
    const float* l0_b3 = (const float*)d_in[6];
    const float* l1_W1 = (const float*)d_in[7];
    const float* l1_b1 = (const float*)d_in[8];
    const float* l1_W2 = (const float*)d_in[9];
    const float* l1_b2 = (const float*)d_in[10];
    const float* l1_W3 = (const float*)d_in[11];
    const float* l1_b3 = (const float*)d_in[12];

    float* outp = (float*)d_out;

    dim3 blk(256);
    dim3 grid(BATCH / TB);   // 512 blocks, 2 per CU
    hipLaunchKernelGGL(kan_fused, grid, blk, 0, stream,
                       x,
                       l0_W1, l0_b1, l0_W2, l0_b2, l0_W3, l0_b3,
                       l1_W1, l1_b1, l1_W2, l1_b2, l1_W3, l1_b3,
                       outp);
}

// Round 5
// 105.523 us; speedup vs baseline: 2.3690x; 1.3753x over previous
//
#include <hip/hip_runtime.h>

// Fused MLPKAN, lane=o layout, 16 batches per weight fetch, spill-free.
// Block = 32 batches, 4 waves; wave = (ih = i-half, bh = batch-half).
//   Layer0: lane = o; 32 i x 16 b per wave; weights coalesced float2/float4.
//   Layer1: lane = iq*16+o1; 8 i x 16 b per wave; iq reduced via shfl_xor.
//   Activations transposed in LDS ([i][b], pad 36) -> b128 broadcasts.
// Hot loops: #pragma unroll 1 + manual 1-deep software pipeline (prefetch
// next weights + next activations into a 2nd register set) -> ~85 live VGPRs,
// no scratch spills (round-4 failure mode: 135 MB spill writes at VGPR cap).

typedef float v2f __attribute__((ext_vector_type(2)));

#define BATCH 16384
#define TB    32

__global__ __launch_bounds__(256, 2) void kan_fused(
    const float* __restrict__ x,
    const float* __restrict__ A1, const float* __restrict__ a1,
    const float* __restrict__ A2, const float* __restrict__ a2,
    const float* __restrict__ A3, const float* __restrict__ a3,
    const float* __restrict__ B1, const float* __restrict__ c1,
    const float* __restrict__ B2, const float* __restrict__ c2,
    const float* __restrict__ B3, const float* __restrict__ c3,
    float* __restrict__ out)
{
    __shared__ float xs[64][36];        // x transposed: xs[i][b]
    __shared__ float hp[2][TB][64];     // layer0 partials per i-half
    __shared__ float ht[64][36];        // h transposed: ht[i][b]
    __shared__ float op[2][TB][16];     // layer1 partials per i-half

    const int t    = threadIdx.x;
    const int lane = t & 63;
    const int wave = t >> 6;
    const int ih   = wave & 1;
    const int bh   = wave >> 1;
    const int bB0  = blockIdx.x * TB;

    // ---- stage x transposed ----
    for (int k = t * 4; k < TB * 64; k += 256 * 4) {
        const float4 v = *(const float4*)(x + (long)bB0 * 64 + k);
        const int b = k >> 6, i = k & 63;
        xs[i][b] = v.x; xs[i + 1][b] = v.y; xs[i + 2][b] = v.z; xs[i + 3][b] = v.w;
    }
    __syncthreads();

    const v2f zz = {0.f, 0.f};

    // ================= layer 0: 64 -> 64 =================
    {
        const int o     = lane;
        const int ibase = 32 * ih;
        const int boff  = 16 * bh;

        auto ldw = [&](int i, v2f& w1, v2f& d1, float4& w2, v2f& d2, v2f& w3, float& b3v) {
            const int n = (i << 6) + o;
            w1  = *(const v2f*)(A1 + 2 * n);
            d1  = *(const v2f*)(a1 + 2 * n);
            w2  = *(const float4*)(A2 + 4 * n);
            d2  = *(const v2f*)(a2 + 2 * n);
            w3  = *(const v2f*)(A3 + 2 * n);
            b3v = a3[n];
        };
        auto ldx = [&](int i, float4* xv) {
            xv[0] = *(const float4*)&xs[i][boff];
            xv[1] = *(const float4*)&xs[i][boff + 4];
            xv[2] = *(const float4*)&xs[i][boff + 8];
            xv[3] = *(const float4*)&xs[i][boff + 12];
        };

        float acc[16];
#pragma unroll
        for (int j = 0; j < 16; ++j) acc[j] = 0.f;
        float bsum = 0.f;

        v2f w1, d1, d2, w3; float4 w2; float b3v;
        float4 xv[4];
        ldw(ibase, w1, d1, w2, d2, w3, b3v);
        ldx(ibase, xv);

#pragma unroll 1
        for (int ii = 0; ii < 32; ++ii) {
            const int inext = ibase + ((ii + 1) & 31);   // wrap: in-bounds
            v2f nw1, nd1, nd2, nw3; float4 nw2; float nb3;
            float4 xn[4];
            ldw(inext, nw1, nd1, nw2, nd2, nw3, nb3);    // in flight during j-loop
            ldx(inext, xn);

            bsum += b3v;
            const v2f c0  = {w2.x, w2.z};
            const v2f c1v = {w2.y, w2.w};
#pragma unroll
            for (int j = 0; j < 16; ++j) {
                const float xb = ((const float*)xv)[j];
                const v2f xd = {xb, xb};
                v2f m = __builtin_elementwise_fma(xd, w1, d1);
                m = __builtin_elementwise_max(m, zz);
                const v2f mm0 = {m.x, m.x};
                const v2f mm1 = {m.y, m.y};
                v2f tt = __builtin_elementwise_fma(c1v, mm1, d2);
                tt = __builtin_elementwise_fma(c0, mm0, tt);
                tt = __builtin_elementwise_max(tt, zz);
                acc[j] = fmaf(w3.x, tt.x, fmaf(w3.y, tt.y, acc[j]));
            }
            w1 = nw1; d1 = nd1; w2 = nw2; d2 = nd2; w3 = nw3; b3v = nb3;
            xv[0] = xn[0]; xv[1] = xn[1]; xv[2] = xn[2]; xv[3] = xn[3];
        }
#pragma unroll
        for (int j = 0; j < 16; ++j)
            hp[ih][boff + j][o] = acc[j] + bsum;
    }
    __syncthreads();

    // ---- combine i-halves + transpose ----
    for (int k = t; k < TB * 64; k += 256) {
        const int b = k >> 6, i = k & 63;
        ht[i][b] = hp[0][b][i] + hp[1][b][i];
    }
    __syncthreads();

    // ================= layer 1: 64 -> 16 =================
    {
        const int o1   = lane & 15;
        const int iq   = lane >> 4;
        const int i0   = 32 * ih + 8 * iq;
        const int boff = 16 * bh;

        auto ldw = [&](int i, v2f& w1, v2f& d1, float4& w2, v2f& d2, v2f& w3, float& b3v) {
            const int n = (i << 4) + o1;
            w1  = *(const v2f*)(B1 + 2 * n);
            d1  = *(const v2f*)(c1 + 2 * n);
            w2  = *(const float4*)(B2 + 4 * n);
            d2  = *(const v2f*)(c2 + 2 * n);
            w3  = *(const v2f*)(B3 + 2 * n);
            b3v = c3[n];
        };
        auto ldh = [&](int i, float4* hv) {
            hv[0] = *(const float4*)&ht[i][boff];
            hv[1] = *(const float4*)&ht[i][boff + 4];
            hv[2] = *(const float4*)&ht[i][boff + 8];
            hv[3] = *(const float4*)&ht[i][boff + 12];
        };

        float acc[16];
#pragma unroll
        for (int j = 0; j < 16; ++j) acc[j] = 0.f;
        float bsum = 0.f;

        v2f w1, d1, d2, w3; float4 w2; float b3v;
        float4 hv[4];
        ldw(i0, w1, d1, w2, d2, w3, b3v);
        ldh(i0, hv);

#pragma unroll 1
        for (int ii = 0; ii < 8; ++ii) {
            const int inext = i0 + ((ii + 1) & 7);
            v2f nw1, nd1, nd2, nw3; float4 nw2; float nb3;
            float4 hn[4];
            ldw(inext, nw1, nd1, nw2, nd2, nw3, nb3);
            ldh(inext, hn);

            bsum += b3v;
            const v2f c0  = {w2.x, w2.z};
            const v2f c1v = {w2.y, w2.w};
#pragma unroll
            for (int j = 0; j < 16; ++j) {
                const float hb = ((const float*)hv)[j];
                const v2f xd = {hb, hb};
                v2f m = __builtin_elementwise_fma(xd, w1, d1);
                m = __builtin_elementwise_max(m, zz);
                const v2f mm0 = {m.x, m.x};
                const v2f mm1 = {m.y, m.y};
                v2f tt = __builtin_elementwise_fma(c1v, mm1, d2);
                tt = __builtin_elementwise_fma(c0, mm0, tt);
                tt = __builtin_elementwise_max(tt, zz);
                acc[j] = fmaf(w3.x, tt.x, fmaf(w3.y, tt.y, acc[j]));
            }
            w1 = nw1; d1 = nd1; w2 = nw2; d2 = nd2; w3 = nw3; b3v = nb3;
            hv[0] = hn[0]; hv[1] = hn[1]; hv[2] = hn[2]; hv[3] = hn[3];
        }

#pragma unroll
        for (int j = 0; j < 16; ++j) {
            float v = acc[j] + bsum;
            v += __shfl_xor(v, 16, 64);
            v += __shfl_xor(v, 32, 64);
            if (iq == 0) op[ih][16 * bh + j][o1] = v;
        }
    }
    __syncthreads();

    // ---- store: out = op[0] + op[1] ----
    if (t < 128) {
        const int f = t * 4;
        const float4 u = *(const float4*)(&op[0][0][0] + f);
        const float4 v = *(const float4*)(&op[1][0][0] + f);
        float4 r;
        r.x = u.x + v.x; r.y = u.y + v.y; r.z = u.z + v.z; r.w = u.w + v.w;
        *(float4*)(out + (long)bB0 * 16 + f) = r;
    }
}

extern "C" void kernel_launch(void* const* d_in, const int* in_sizes, int n_in,
                              void* d_out, int out_size, void* d_ws, size_t ws_size,
                              hipStream_t stream) {
    const float* x     = (const float*)d_in[0];
    const float* l0_W1 = (const float*)d_in[1];
    const float* l0_b1 = (const float*)d_in[2];
    const float* l0_W2 = (const float*)d_in[3];
    const float* l0_b2 = (const float*)d_in[4];
    const float* l0_W3 = (const float*)d_in[5];
    const float* l0_b3 = (const float*)d_in[6];
    const float* l1_W1 = (const float*)d_in[7];
    const float* l1_b1 = (const float*)d_in[8];
    const float* l1_W2 = (const float*)d_in[9];
    const float* l1_b2 = (const float*)d_in[10];
    const float* l1_W3 = (const float*)d_in[11];
    const float* l1_b3 = (const float*)d_in[12];

    float* outp = (float*)d_out;

    dim3 blk(256);
    dim3 grid(BATCH / TB);   // 512 blocks, 2 per CU
    hipLaunchKernelGGL(kan_fused, grid, blk, 0, stream,
                       x,
                       l0_W1, l0_b1, l0_W2, l0_b2, l0_W3, l0_b3,
                       l1_W1, l1_b1, l1_W2, l1_b2, l1_W3, l1_b3,
                       outp);
}

// Round 6
// 102.136 us; speedup vs baseline: 2.4476x; 1.0332x over previous
//
#include <hip/hip_runtime.h>

// Fused MLPKAN. Block = 512 threads (8 waves), TB = 32 batches.
// Wave = (iq = i-quarter, bh = batch-half): 16 i x 16 b per wave.
//   Layer0: lane = o (64 coalesced lane-distinct subnets per i).
//   Layer1: lane = ig*16+o1; lane covers 4 i x 16 b; ig reduced via shfl_xor.
//   Activations transposed in LDS ([i][b], pad 36) -> b128 broadcasts.
// Grid = 512 -> 2 blocks/CU -> 16 waves/CU -> 4 waves/SIMD (TLP hides weight
// L2 latency + LDS latency; round-5 had only 2/SIMD and stalled ~60%).
// Weights: 1-deep software-pipelined global prefetch; VGPR target <= 128.

typedef float v2f __attribute__((ext_vector_type(2)));

#define BATCH 16384
#define TB    32

__global__ __launch_bounds__(512, 4) void kan_fused(
    const float* __restrict__ x,
    const float* __restrict__ A1, const float* __restrict__ a1,
    const float* __restrict__ A2, const float* __restrict__ a2,
    const float* __restrict__ A3, const float* __restrict__ a3,
    const float* __restrict__ B1, const float* __restrict__ c1,
    const float* __restrict__ B2, const float* __restrict__ c2,
    const float* __restrict__ B3, const float* __restrict__ c3,
    float* __restrict__ out)
{
    __shared__ float xs[64][36];        // x transposed: xs[i][b]
    __shared__ float hp[4][TB][64];     // layer0 partials per i-quarter
    __shared__ float ht[64][36];        // h transposed: ht[i][b]
    __shared__ float op[4][TB][16];     // layer1 partials per i-quarter

    const int t    = threadIdx.x;
    const int lane = t & 63;
    const int wave = t >> 6;            // 0..7
    const int iq   = wave & 3;          // i-quarter: [16*iq, 16*iq+16)
    const int bh   = wave >> 2;         // batch-half: [16*bh, 16*bh+16)
    const int bB0  = blockIdx.x * TB;

    // ---- stage x transposed: 2048 floats, 512 thr x float4 ----
    {
        const int k = t * 4;
        const float4 v = *(const float4*)(x + (long)bB0 * 64 + k);
        const int b = k >> 6, i = k & 63;
        xs[i][b] = v.x; xs[i + 1][b] = v.y; xs[i + 2][b] = v.z; xs[i + 3][b] = v.w;
    }
    __syncthreads();

    const v2f zz = {0.f, 0.f};
    const int boff = 16 * bh;

    // ================= layer 0: 64 -> 64 =================
    {
        const int o  = lane;
        const int i0 = 16 * iq;

        auto ldw = [&](int i, v2f& w1, v2f& d1, float4& w2, v2f& d2, v2f& w3, float& b3v) {
            const int n = (i << 6) + o;
            w1  = *(const v2f*)(A1 + 2 * n);
            d1  = *(const v2f*)(a1 + 2 * n);
            w2  = *(const float4*)(A2 + 4 * n);
            d2  = *(const v2f*)(a2 + 2 * n);
            w3  = *(const v2f*)(A3 + 2 * n);
            b3v = a3[n];
        };

        float acc[16];
#pragma unroll
        for (int j = 0; j < 16; ++j) acc[j] = 0.f;
        float bsum = 0.f;

        v2f w1, d1, d2, w3; float4 w2; float b3v;
        ldw(i0, w1, d1, w2, d2, w3, b3v);

#pragma unroll 1
        for (int ii = 0; ii < 16; ++ii) {
            const int i = i0 + ii;
            v2f nw1, nd1, nd2, nw3; float4 nw2; float nb3;
            ldw(i0 + ((ii + 1) & 15), nw1, nd1, nw2, nd2, nw3, nb3);  // in flight

            const float4 xv0 = *(const float4*)&xs[i][boff];          // ds b128
            const float4 xv1 = *(const float4*)&xs[i][boff + 4];
            const float4 xv2 = *(const float4*)&xs[i][boff + 8];
            const float4 xv3 = *(const float4*)&xs[i][boff + 12];
            const float4 xv[4] = {xv0, xv1, xv2, xv3};

            bsum += b3v;
            const v2f c0  = {w2.x, w2.z};
            const v2f c1v = {w2.y, w2.w};
#pragma unroll
            for (int j = 0; j < 16; ++j) {
                const float xb = ((const float*)xv)[j];
                const v2f xd = {xb, xb};
                v2f m = __builtin_elementwise_fma(xd, w1, d1);
                m = __builtin_elementwise_max(m, zz);
                const v2f mm0 = {m.x, m.x};
                const v2f mm1 = {m.y, m.y};
                v2f tt = __builtin_elementwise_fma(c1v, mm1, d2);
                tt = __builtin_elementwise_fma(c0, mm0, tt);
                tt = __builtin_elementwise_max(tt, zz);
                acc[j] = fmaf(w3.x, tt.x, fmaf(w3.y, tt.y, acc[j]));
            }
            w1 = nw1; d1 = nd1; w2 = nw2; d2 = nd2; w3 = nw3; b3v = nb3;
        }
#pragma unroll
        for (int j = 0; j < 16; ++j)
            hp[iq][boff + j][o] = acc[j] + bsum;   // rows bank-aligned: 2-way, free
    }
    __syncthreads();

    // ---- combine i-quarters + transpose: ht[i][b] = sum_q hp[q][b][i] ----
    for (int k = t; k < TB * 64; k += 512) {
        const int b = k >> 6, i = k & 63;
        ht[i][b] = hp[0][b][i] + hp[1][b][i] + hp[2][b][i] + hp[3][b][i];
    }
    __syncthreads();

    // ================= layer 1: 64 -> 16 =================
    {
        const int o1 = lane & 15;
        const int ig = lane >> 4;          // 4 i-subgroups of 4
        const int i0 = 16 * iq + 4 * ig;

        auto ldw = [&](int i, v2f& w1, v2f& d1, float4& w2, v2f& d2, v2f& w3, float& b3v) {
            const int n = (i << 4) + o1;
            w1  = *(const v2f*)(B1 + 2 * n);
            d1  = *(const v2f*)(c1 + 2 * n);
            w2  = *(const float4*)(B2 + 4 * n);
            d2  = *(const v2f*)(c2 + 2 * n);
            w3  = *(const v2f*)(B3 + 2 * n);
            b3v = c3[n];
        };

        float acc[16];
#pragma unroll
        for (int j = 0; j < 16; ++j) acc[j] = 0.f;
        float bsum = 0.f;

        v2f w1, d1, d2, w3; float4 w2; float b3v;
        ldw(i0, w1, d1, w2, d2, w3, b3v);

#pragma unroll 1
        for (int ii = 0; ii < 4; ++ii) {
            const int i = i0 + ii;
            v2f nw1, nd1, nd2, nw3; float4 nw2; float nb3;
            ldw(i0 + ((ii + 1) & 3), nw1, nd1, nw2, nd2, nw3, nb3);

            const float4 hv0 = *(const float4*)&ht[i][boff];
            const float4 hv1 = *(const float4*)&ht[i][boff + 4];
            const float4 hv2 = *(const float4*)&ht[i][boff + 8];
            const float4 hv3 = *(const float4*)&ht[i][boff + 12];
            const float4 hv[4] = {hv0, hv1, hv2, hv3};

            bsum += b3v;
            const v2f c0  = {w2.x, w2.z};
            const v2f c1v = {w2.y, w2.w};
#pragma unroll
            for (int j = 0; j < 16; ++j) {
                const float hb = ((const float*)hv)[j];
                const v2f xd = {hb, hb};
                v2f m = __builtin_elementwise_fma(xd, w1, d1);
                m = __builtin_elementwise_max(m, zz);
                const v2f mm0 = {m.x, m.x};
                const v2f mm1 = {m.y, m.y};
                v2f tt = __builtin_elementwise_fma(c1v, mm1, d2);
                tt = __builtin_elementwise_fma(c0, mm0, tt);
                tt = __builtin_elementwise_max(tt, zz);
                acc[j] = fmaf(w3.x, tt.x, fmaf(w3.y, tt.y, acc[j]));
            }
            w1 = nw1; d1 = nd1; w2 = nw2; d2 = nd2; w3 = nw3; b3v = nb3;
        }

        // reduce over ig (lanes 16 apart), write per-iq partial
#pragma unroll
        for (int j = 0; j < 16; ++j) {
            float v = acc[j] + bsum;
            v += __shfl_xor(v, 16, 64);
            v += __shfl_xor(v, 32, 64);
            if (ig == 0) op[iq][boff + j][o1] = v;
        }
    }
    __syncthreads();

    // ---- store: out = sum_q op[q], 512 floats, float4 coalesced ----
    if (t < 128) {
        const int f = t * 4;
        const float4 p0 = *(const float4*)(&op[0][0][0] + f);
        const float4 p1 = *(const float4*)(&op[1][0][0] + f);
        const float4 p2 = *(const float4*)(&op[2][0][0] + f);
        const float4 p3 = *(const float4*)(&op[3][0][0] + f);
        float4 r;
        r.x = p0.x + p1.x + p2.x + p3.x;
        r.y = p0.y + p1.y + p2.y + p3.y;
        r.z = p0.z + p1.z + p2.z + p3.z;
        r.w = p0.w + p1.w + p2.w + p3.w;
        *(float4*)(out + (long)bB0 * 16 + f) = r;
    }
}

extern "C" void kernel_launch(void* const* d_in, const int* in_sizes, int n_in,
                              void* d_out, int out_size, void* d_ws, size_t ws_size,
                              hipStream_t stream) {
    const float* x     = (const float*)d_in[0];
    const float* l0_W1 = (const float*)d_in[1];
    const float* l0_b1 = (const float*)d_in[2];
    const float* l0_W2 = (const float*)d_in[3];
    const float* l0_b2 = (const float*)d_in[4];
    const float* l0_W3 = (const float*)d_in[5];
    const float* l0_b3 = (const float*)d_in[6];
    const float* l1_W1 = (const float*)d_in[7];
    const float* l1_b1 = (const float*)d_in[8];
    const float* l1_W2 = (const float*)d_in[9];
    const float* l1_b2 = (const float*)d_in[10];
    const float* l1_W3 = (const float*)d_in[11];
    const float* l1_b3 = (const float*)d_in[12];

    float* outp = (float*)d_out;

    dim3 blk(512);
    dim3 grid(BATCH / TB);   // 512 blocks, 2 per CU
    hipLaunchKernelGGL(kan_fused, grid, blk, 0, stream,
                       x,
                       l0_W1, l0_b1, l0_W2, l0_b2, l0_W3, l0_b3,
                       l1_W1, l1_b1, l1_W2, l1_b2, l1_W3, l1_b3,
                       outp);
}